// Round 1
// baseline (247.309 us; speedup 1.0000x reference)
//
#include <hip/hip_runtime.h>
#include <math.h>

#define BB 16
#define HH 256
#define WW 256
#define CO 64

// ws layout in floats
#define OFF_CHSUM 0      // [64]
#define OFF_CHSQ  64     // [64]
#define OFF_A     128    // [64]  rsig * bn_w
#define OFF_B     192    // [64]  bn_b - mu * A
#define OFF_FEAT  256    // [16*64] pooled relu sums (pre-division)
#define OFF_SRF   1280   // [16*3*31]
#define SRF_N     (16 * 93)

__global__ void k_init(float* __restrict__ ws) {
    int i = blockIdx.x * 256 + threadIdx.x;
    if (i < 1280) ws[i] = 0.f;
}

__device__ __forceinline__ void loadrow(const float* __restrict__ xb, int rr, int col,
                                        float* dst) {
    if (rr < 0 || rr >= HH) {
#pragma unroll
        for (int k = 0; k < 9; ++k) dst[k] = 0.f;
        return;
    }
    const float* p = xb + rr * (WW * 3);
#pragma unroll
    for (int kw = 0; kw < 3; ++kw) {
        int cc = col - 1 + kw;
        if (cc >= 0 && cc < WW) {
            dst[kw * 3 + 0] = p[cc * 3 + 0];
            dst[kw * 3 + 1] = p[cc * 3 + 1];
            dst[kw * 3 + 2] = p[cc * 3 + 2];
        } else {
            dst[kw * 3 + 0] = 0.f;
            dst[kw * 3 + 1] = 0.f;
            dst[kw * 3 + 2] = 0.f;
        }
    }
}

__device__ __forceinline__ float dorow(const float* wt, float bias,
                                       const float* r0, const float* r1, const float* r2) {
    float y = bias;
#pragma unroll
    for (int ci = 0; ci < 3; ++ci) {
#pragma unroll
        for (int kw = 0; kw < 3; ++kw) {
            y = fmaf(wt[ci * 9 + 0 * 3 + kw], r0[kw * 3 + ci], y);
            y = fmaf(wt[ci * 9 + 1 * 3 + kw], r1[kw * 3 + ci], y);
            y = fmaf(wt[ci * 9 + 2 * 3 + kw], r2[kw * 3 + ci], y);
        }
    }
    return y;
}

// MODE 0: accumulate per-channel sum/sumsq.  MODE 1: BN+ReLU, accumulate per-(b,c) pool sum.
template <int MODE>
__global__ __launch_bounds__(256) void k_conv(const float* __restrict__ x,
                                              const float* __restrict__ cw,
                                              const float* __restrict__ cb,
                                              float* __restrict__ ws) {
    const int lane = threadIdx.x & 63;   // output channel
    const int wv   = threadIdx.x >> 6;   // wave id 0..3
    const int b    = blockIdx.y;
    const int col  = (blockIdx.x << 2) + wv;  // image column 0..255

    float wt[27];
#pragma unroll
    for (int k = 0; k < 27; ++k) wt[k] = cw[lane * 27 + k];
    const float bias = cb[lane];

    float A = 0.f, Bc = 0.f;
    if (MODE == 1) {
        A  = ws[OFF_A + lane];
        Bc = ws[OFF_B + lane];
    }

    const float* xb = x + (size_t)b * (HH * WW * 3);

    float w0[9], w1[9], w2[9];
    loadrow(xb, -1, col, w0);
    loadrow(xb, 0, col, w1);
    loadrow(xb, 1, col, w2);

    float acc_s = 0.f, acc_q = 0.f;

#define DO_ONE(A0, A1, A2)                                   \
    {                                                        \
        float y = dorow(wt, bias, A0, A1, A2);               \
        if (MODE == 0) {                                     \
            acc_s += y;                                      \
            acc_q = fmaf(y, y, acc_q);                       \
        } else {                                             \
            float t = fmaf(y, A, Bc);                        \
            t = fmaxf(t, 0.f);                               \
            acc_s += t;                                      \
        }                                                    \
    }

    for (int r = 0; r < 255; r += 3) {
        DO_ONE(w0, w1, w2); loadrow(xb, r + 2, col, w0);
        DO_ONE(w1, w2, w0); loadrow(xb, r + 3, col, w1);
        DO_ONE(w2, w0, w1); loadrow(xb, r + 4, col, w2);
    }
    // r = 255: window rows 254,255,256(zeros) are in (w0,w1,w2)
    DO_ONE(w0, w1, w2);
#undef DO_ONE

    __shared__ float red[4][64][2];
    red[wv][lane][0] = acc_s;
    if (MODE == 0) red[wv][lane][1] = acc_q;
    __syncthreads();
    if (wv == 0) {
        float S = red[0][lane][0] + red[1][lane][0] + red[2][lane][0] + red[3][lane][0];
        if (MODE == 0) {
            float Q = red[0][lane][1] + red[1][lane][1] + red[2][lane][1] + red[3][lane][1];
            atomicAdd(&ws[OFF_CHSUM + lane], S);
            atomicAdd(&ws[OFF_CHSQ + lane], Q);
        } else {
            atomicAdd(&ws[OFF_FEAT + b * 64 + lane], S);
        }
    }
}

__global__ void k_stats(const float* __restrict__ bn_w, const float* __restrict__ bn_b,
                        float* __restrict__ ws) {
    int c = threadIdx.x;
    if (c < 64) {
        const float invN = 1.f / (float)(BB * HH * WW);
        float mu  = ws[OFF_CHSUM + c] * invN;
        float var = ws[OFF_CHSQ + c] * invN - mu * mu;
        float rs  = rsqrtf(var + 1e-5f);
        float A   = rs * bn_w[c];
        ws[OFF_A + c] = A;
        ws[OFF_B + c] = bn_b[c] - mu * A;
    }
}

__global__ void k_volt(const float* __restrict__ fcw, const float* __restrict__ fcb,
                       float* __restrict__ ws) {
    __shared__ float sv[16 * 3];
    int t = threadIdx.x;
    if (t < 16) {
        const float inv = 1.f / 65536.f;
        float raw[5];
#pragma unroll
        for (int j = 0; j < 5; ++j) {
            float a = fcb[j];
            for (int c2 = 0; c2 < 64; ++c2)
                a = fmaf(fcw[j * 64 + c2], ws[OFF_FEAT + t * 64 + c2] * inv, a);
            raw[j] = a;
        }
        // optimal 9-comparator sorting network, n=5 (constant indices only)
#define CS(i, j)                              \
        {                                     \
            float lo = fminf(raw[i], raw[j]); \
            float hi = fmaxf(raw[i], raw[j]); \
            raw[i] = lo;                      \
            raw[j] = hi;                      \
        }
        CS(0, 1) CS(3, 4) CS(2, 4) CS(2, 3) CS(0, 3) CS(0, 2) CS(1, 4) CS(1, 3) CS(1, 2)
#undef CS
        float mn = raw[0], mx = raw[4];
        float s = 10.f / (mx - mn + 1e-8f);
        sv[t * 3 + 0] = (raw[1] - mn) * s;
        sv[t * 3 + 1] = (raw[2] - mn) * s;
        sv[t * 3 + 2] = (raw[3] - mn) * s;
    }
    __syncthreads();
    for (int i = t; i < SRF_N; i += 256) {
        int b = i / 93, rr = i % 93, c2 = rr / 31, a = rr % 31;
        float band = 400.f + (300.f * (float)a) / 31.f;
        float v = sv[b * 3 + c2];
        // 0.5 - 0.5*cos(2*pi*(-0.01)/v) == sin^2(pi*0.01/v)  (exact, no cancellation)
        float sh = sinf(0.031415926535897934f / v);
        ws[OFF_SRF + i] = (sh * sh) / (band * 1e-6f);
    }
}

__global__ __launch_bounds__(256) void k_apply(const float* __restrict__ xh,
                                               const float* __restrict__ ws,
                                               float* __restrict__ out) {
    __shared__ float4 s_srf[31];        // [a] -> (srf_c0, srf_c1, srf_c2, pad)
    __shared__ float s_x[256 * 31];     // 256 pixels x 31 bands
    __shared__ float s_o[256 * 3];
    int t = threadIdx.x;
    int blk = blockIdx.x;               // 4096 blocks, 256 per image
    int b = blk >> 8;
    size_t pix0 = (size_t)blk << 8;

    if (t < 124) {
        int a = t >> 2, c2 = t & 3;
        ((float*)s_srf)[t] = (c2 < 3) ? ws[OFF_SRF + b * 93 + c2 * 31 + a] : 0.f;
    }
    const float4* xg = (const float4*)(xh + pix0 * 31);  // 31744*blk bytes: 16B-aligned
    float4* sx4 = (float4*)s_x;
#pragma unroll
    for (int i = 0; i < 8; ++i) {
        int idx = t + (i << 8);
        if (idx < 1984) sx4[idx] = xg[idx];
    }
    __syncthreads();

    float a0 = 0.f, a1 = 0.f, a2 = 0.f;
    const float* px = s_x + t * 31;
#pragma unroll
    for (int a = 0; a < 31; ++a) {
        float v = px[a];
        float4 s = s_srf[a];
        a0 = fmaf(v, s.x, a0);
        a1 = fmaf(v, s.y, a1);
        a2 = fmaf(v, s.z, a2);
    }
    s_o[t * 3 + 0] = a0;
    s_o[t * 3 + 1] = a1;
    s_o[t * 3 + 2] = a2;
    __syncthreads();
    float* ob = out + pix0 * 3;
#pragma unroll
    for (int i = 0; i < 3; ++i) ob[t + (i << 8)] = s_o[t + (i << 8)];
}

extern "C" void kernel_launch(void* const* d_in, const int* in_sizes, int n_in,
                              void* d_out, int out_size, void* d_ws, size_t ws_size,
                              hipStream_t stream) {
    const float* x    = (const float*)d_in[0];
    const float* xhsi = (const float*)d_in[1];
    const float* cw   = (const float*)d_in[2];
    const float* cb   = (const float*)d_in[3];
    const float* bnw  = (const float*)d_in[4];
    const float* bnb  = (const float*)d_in[5];
    const float* fcw  = (const float*)d_in[6];
    const float* fcb  = (const float*)d_in[7];
    float* out = (float*)d_out;
    float* ws  = (float*)d_ws;

    hipLaunchKernelGGL(k_init, dim3(5), dim3(256), 0, stream, ws);
    hipLaunchKernelGGL((k_conv<0>), dim3(64, 16), dim3(256), 0, stream, x, cw, cb, ws);
    hipLaunchKernelGGL(k_stats, dim3(1), dim3(64), 0, stream, bnw, bnb, ws);
    hipLaunchKernelGGL((k_conv<1>), dim3(64, 16), dim3(256), 0, stream, x, cw, cb, ws);
    hipLaunchKernelGGL(k_volt, dim3(1), dim3(256), 0, stream, fcw, fcb, ws);
    hipLaunchKernelGGL(k_apply, dim3(4096), dim3(256), 0, stream, xhsi, ws, out);
}

// Round 2
// 241.495 us; speedup vs baseline: 1.0241x; 1.0241x over previous
//
#include <hip/hip_runtime.h>
#include <math.h>

#define BB 16
#define HH 256
#define WW 256
#define PW 258

// ws layout in floats
#define OFF_CHSUM 0      // [64]
#define OFF_CHSQ  64     // [64]
#define OFF_A     128    // [64]  rsig * bn_w
#define OFF_B     192    // [64]  bn_b - mu * A
#define OFF_FEAT  256    // [16*64] pooled relu sums (pre-division)
#define OFF_SRF   1280   // [16*3*31]
#define SRF_N     (16 * 93)
#define OFF_X4    4096   // padded input: 16 x 258 x 258 x float4
#define X4_FLOATS (16 * PW * PW * 4)
#define WS_NEED_BYTES ((size_t)(OFF_X4 + X4_FLOATS) * 4)

__global__ void k_init(float* __restrict__ ws) {
    int i = blockIdx.x * 256 + threadIdx.x;
    if (i < 1280) ws[i] = 0.f;
}

// ---------------- padded-layout fast path ----------------

__global__ __launch_bounds__(256) void k_pad(const float* __restrict__ x,
                                             float* __restrict__ ws) {
    int b = blockIdx.y;
    int i = blockIdx.x * 256 + threadIdx.x;
    if (i >= PW * PW) return;
    int pr = i / PW, pc = i % PW;
    float4 v = make_float4(0.f, 0.f, 0.f, 0.f);
    if (pr >= 1 && pr <= HH && pc >= 1 && pc <= WW) {
        const float* p = x + (((size_t)b * HH + (pr - 1)) * WW + (pc - 1)) * 3;
        v.x = p[0]; v.y = p[1]; v.z = p[2];
    }
    ((float4*)(ws + OFF_X4))[((size_t)b * PW + pr) * PW + pc] = v;
}

// MODE 0: per-channel sum/sumsq.  MODE 1: BN+ReLU, per-(b,c) pool sum.
template <int MODE>
__global__ __launch_bounds__(256) void k_convp(const float* __restrict__ cw,
                                               const float* __restrict__ cb,
                                               float* __restrict__ ws) {
    const int lane = threadIdx.x & 63;   // output channel
    const int wv   = threadIdx.x >> 6;
    const int b    = blockIdx.y;
    const int col  = blockIdx.x * 4 + wv;   // output col 0..255
    const int r0   = blockIdx.z * 128;      // output row base

    float wt[27];
#pragma unroll
    for (int k = 0; k < 27; ++k) wt[k] = cw[lane * 27 + k];
    const float bias = cb[lane];
    float A = 0.f, Bc = 0.f;
    if (MODE == 1) { A = ws[OFF_A + lane]; Bc = ws[OFF_B + lane]; }

    const float4* rp = (const float4*)(ws + OFF_X4) + ((size_t)(b * PW + r0)) * PW + col;

    float4 R0[3], R1[3], R2[3], R3[3];
#define LD(R) { R[0] = rp[0]; R[1] = rp[1]; R[2] = rp[2]; rp += PW; }
    LD(R0) LD(R1) LD(R2)

    float acc_s = 0.f, acc_q = 0.f;

#define PX(RA, RB, RC)                                                        \
    {                                                                         \
        float y0 = bias, y1 = 0.f, y2 = 0.f;                                  \
        y0 = fmaf(wt[0], RA[0].x, y0); y0 = fmaf(wt[1], RA[1].x, y0);         \
        y0 = fmaf(wt[2], RA[2].x, y0); y0 = fmaf(wt[3], RB[0].x, y0);         \
        y0 = fmaf(wt[4], RB[1].x, y0); y0 = fmaf(wt[5], RB[2].x, y0);         \
        y0 = fmaf(wt[6], RC[0].x, y0); y0 = fmaf(wt[7], RC[1].x, y0);         \
        y0 = fmaf(wt[8], RC[2].x, y0);                                        \
        y1 = fmaf(wt[9], RA[0].y, y1); y1 = fmaf(wt[10], RA[1].y, y1);        \
        y1 = fmaf(wt[11], RA[2].y, y1); y1 = fmaf(wt[12], RB[0].y, y1);       \
        y1 = fmaf(wt[13], RB[1].y, y1); y1 = fmaf(wt[14], RB[2].y, y1);       \
        y1 = fmaf(wt[15], RC[0].y, y1); y1 = fmaf(wt[16], RC[1].y, y1);       \
        y1 = fmaf(wt[17], RC[2].y, y1);                                       \
        y2 = fmaf(wt[18], RA[0].z, y2); y2 = fmaf(wt[19], RA[1].z, y2);       \
        y2 = fmaf(wt[20], RA[2].z, y2); y2 = fmaf(wt[21], RB[0].z, y2);       \
        y2 = fmaf(wt[22], RB[1].z, y2); y2 = fmaf(wt[23], RB[2].z, y2);       \
        y2 = fmaf(wt[24], RC[0].z, y2); y2 = fmaf(wt[25], RC[1].z, y2);       \
        y2 = fmaf(wt[26], RC[2].z, y2);                                       \
        float y = (y0 + y1) + y2;                                             \
        if (MODE == 0) {                                                      \
            acc_s += y;                                                       \
            acc_q = fmaf(y, y, acc_q);                                        \
        } else {                                                              \
            float t = fmaxf(fmaf(y, A, Bc), 0.f);                             \
            acc_s += t;                                                       \
        }                                                                     \
    }

#pragma unroll 1
    for (int i = 0; i < 31; ++i) {
        PX(R0, R1, R2) LD(R3)
        PX(R1, R2, R3) LD(R0)
        PX(R2, R3, R0) LD(R1)
        PX(R3, R0, R1) LD(R2)
    }
    // pixels 124..127 (rows up to r0+129 in padded coords; max 257 — in bounds)
    PX(R0, R1, R2) LD(R3)
    PX(R1, R2, R3) LD(R0)
    PX(R2, R3, R0) LD(R1)
    PX(R3, R0, R1)
#undef PX
#undef LD

    __shared__ float red[4][64][2];
    red[wv][lane][0] = acc_s;
    if (MODE == 0) red[wv][lane][1] = acc_q;
    __syncthreads();
    if (wv == 0) {
        float S = red[0][lane][0] + red[1][lane][0] + red[2][lane][0] + red[3][lane][0];
        if (MODE == 0) {
            float Q = red[0][lane][1] + red[1][lane][1] + red[2][lane][1] + red[3][lane][1];
            atomicAdd(&ws[OFF_CHSUM + lane], S);
            atomicAdd(&ws[OFF_CHSQ + lane], Q);
        } else {
            atomicAdd(&ws[OFF_FEAT + b * 64 + lane], S);
        }
    }
}

// ---------------- fallback (round-1) conv ----------------

__device__ __forceinline__ void loadrow(const float* __restrict__ xb, int rr, int col,
                                        float* dst) {
    if (rr < 0 || rr >= HH) {
#pragma unroll
        for (int k = 0; k < 9; ++k) dst[k] = 0.f;
        return;
    }
    const float* p = xb + rr * (WW * 3);
#pragma unroll
    for (int kw = 0; kw < 3; ++kw) {
        int cc = col - 1 + kw;
        if (cc >= 0 && cc < WW) {
            dst[kw * 3 + 0] = p[cc * 3 + 0];
            dst[kw * 3 + 1] = p[cc * 3 + 1];
            dst[kw * 3 + 2] = p[cc * 3 + 2];
        } else {
            dst[kw * 3 + 0] = 0.f; dst[kw * 3 + 1] = 0.f; dst[kw * 3 + 2] = 0.f;
        }
    }
}

__device__ __forceinline__ float dorow(const float* wt, float bias,
                                       const float* r0, const float* r1, const float* r2) {
    float y = bias;
#pragma unroll
    for (int ci = 0; ci < 3; ++ci) {
#pragma unroll
        for (int kw = 0; kw < 3; ++kw) {
            y = fmaf(wt[ci * 9 + 0 * 3 + kw], r0[kw * 3 + ci], y);
            y = fmaf(wt[ci * 9 + 1 * 3 + kw], r1[kw * 3 + ci], y);
            y = fmaf(wt[ci * 9 + 2 * 3 + kw], r2[kw * 3 + ci], y);
        }
    }
    return y;
}

template <int MODE>
__global__ __launch_bounds__(256) void k_conv(const float* __restrict__ x,
                                              const float* __restrict__ cw,
                                              const float* __restrict__ cb,
                                              float* __restrict__ ws) {
    const int lane = threadIdx.x & 63;
    const int wv   = threadIdx.x >> 6;
    const int b    = blockIdx.y;
    const int col  = (blockIdx.x << 2) + wv;

    float wt[27];
#pragma unroll
    for (int k = 0; k < 27; ++k) wt[k] = cw[lane * 27 + k];
    const float bias = cb[lane];

    float A = 0.f, Bc = 0.f;
    if (MODE == 1) { A = ws[OFF_A + lane]; Bc = ws[OFF_B + lane]; }

    const float* xb = x + (size_t)b * (HH * WW * 3);

    float w0[9], w1[9], w2[9];
    loadrow(xb, -1, col, w0);
    loadrow(xb, 0, col, w1);
    loadrow(xb, 1, col, w2);

    float acc_s = 0.f, acc_q = 0.f;

#define DO_ONE(A0, A1, A2)                                   \
    {                                                        \
        float y = dorow(wt, bias, A0, A1, A2);               \
        if (MODE == 0) {                                     \
            acc_s += y;                                      \
            acc_q = fmaf(y, y, acc_q);                       \
        } else {                                             \
            float t = fmaf(y, A, Bc);                        \
            t = fmaxf(t, 0.f);                               \
            acc_s += t;                                      \
        }                                                    \
    }

    for (int r = 0; r < 255; r += 3) {
        DO_ONE(w0, w1, w2); loadrow(xb, r + 2, col, w0);
        DO_ONE(w1, w2, w0); loadrow(xb, r + 3, col, w1);
        DO_ONE(w2, w0, w1); loadrow(xb, r + 4, col, w2);
    }
    DO_ONE(w0, w1, w2);
#undef DO_ONE

    __shared__ float red[4][64][2];
    red[wv][lane][0] = acc_s;
    if (MODE == 0) red[wv][lane][1] = acc_q;
    __syncthreads();
    if (wv == 0) {
        float S = red[0][lane][0] + red[1][lane][0] + red[2][lane][0] + red[3][lane][0];
        if (MODE == 0) {
            float Q = red[0][lane][1] + red[1][lane][1] + red[2][lane][1] + red[3][lane][1];
            atomicAdd(&ws[OFF_CHSUM + lane], S);
            atomicAdd(&ws[OFF_CHSQ + lane], Q);
        } else {
            atomicAdd(&ws[OFF_FEAT + b * 64 + lane], S);
        }
    }
}

// ---------------- tail kernels ----------------

__global__ void k_stats(const float* __restrict__ bn_w, const float* __restrict__ bn_b,
                        float* __restrict__ ws) {
    int c = threadIdx.x;
    if (c < 64) {
        const float invN = 1.f / (float)(BB * HH * WW);
        float mu  = ws[OFF_CHSUM + c] * invN;
        float var = ws[OFF_CHSQ + c] * invN - mu * mu;
        float rs  = rsqrtf(var + 1e-5f);
        float A   = rs * bn_w[c];
        ws[OFF_A + c] = A;
        ws[OFF_B + c] = bn_b[c] - mu * A;
    }
}

__global__ void k_volt(const float* __restrict__ fcw, const float* __restrict__ fcb,
                       float* __restrict__ ws) {
    __shared__ float sv[16 * 3];
    int t = threadIdx.x;
    if (t < 16) {
        const float inv = 1.f / 65536.f;
        float raw[5];
#pragma unroll
        for (int j = 0; j < 5; ++j) {
            float a = fcb[j];
            for (int c2 = 0; c2 < 64; ++c2)
                a = fmaf(fcw[j * 64 + c2], ws[OFF_FEAT + t * 64 + c2] * inv, a);
            raw[j] = a;
        }
#define CS(i, j)                              \
        {                                     \
            float lo = fminf(raw[i], raw[j]); \
            float hi = fmaxf(raw[i], raw[j]); \
            raw[i] = lo;                      \
            raw[j] = hi;                      \
        }
        CS(0, 1) CS(3, 4) CS(2, 4) CS(2, 3) CS(0, 3) CS(0, 2) CS(1, 4) CS(1, 3) CS(1, 2)
#undef CS
        float mn = raw[0], mx = raw[4];
        float s = 10.f / (mx - mn + 1e-8f);
        sv[t * 3 + 0] = (raw[1] - mn) * s;
        sv[t * 3 + 1] = (raw[2] - mn) * s;
        sv[t * 3 + 2] = (raw[3] - mn) * s;
    }
    __syncthreads();
    for (int i = t; i < SRF_N; i += 256) {
        int b = i / 93, rr = i % 93, c2 = rr / 31, a = rr % 31;
        float band = 400.f + (300.f * (float)a) / 31.f;
        float v = sv[b * 3 + c2];
        float sh = sinf(0.031415926535897934f / v);
        ws[OFF_SRF + i] = (sh * sh) / (band * 1e-6f);
    }
}

__global__ __launch_bounds__(256) void k_apply(const float* __restrict__ xh,
                                               const float* __restrict__ ws,
                                               float* __restrict__ out) {
    __shared__ float4 s_srf[31];
    __shared__ float s_x[256 * 31];
    __shared__ float s_o[256 * 3];
    int t = threadIdx.x;
    int blk = blockIdx.x;
    int b = blk >> 8;
    size_t pix0 = (size_t)blk << 8;

    if (t < 124) {
        int a = t >> 2, c2 = t & 3;
        ((float*)s_srf)[t] = (c2 < 3) ? ws[OFF_SRF + b * 93 + c2 * 31 + a] : 0.f;
    }
    const float4* xg = (const float4*)(xh + pix0 * 31);
    float4* sx4 = (float4*)s_x;
#pragma unroll
    for (int i = 0; i < 8; ++i) {
        int idx = t + (i << 8);
        if (idx < 1984) sx4[idx] = xg[idx];
    }
    __syncthreads();

    float a0 = 0.f, a1 = 0.f, a2 = 0.f;
    const float* px = s_x + t * 31;
#pragma unroll
    for (int a = 0; a < 31; ++a) {
        float v = px[a];
        float4 s = s_srf[a];
        a0 = fmaf(v, s.x, a0);
        a1 = fmaf(v, s.y, a1);
        a2 = fmaf(v, s.z, a2);
    }
    s_o[t * 3 + 0] = a0;
    s_o[t * 3 + 1] = a1;
    s_o[t * 3 + 2] = a2;
    __syncthreads();
    float* ob = out + pix0 * 3;
#pragma unroll
    for (int i = 0; i < 3; ++i) ob[t + (i << 8)] = s_o[t + (i << 8)];
}

extern "C" void kernel_launch(void* const* d_in, const int* in_sizes, int n_in,
                              void* d_out, int out_size, void* d_ws, size_t ws_size,
                              hipStream_t stream) {
    const float* x    = (const float*)d_in[0];
    const float* xhsi = (const float*)d_in[1];
    const float* cw   = (const float*)d_in[2];
    const float* cb   = (const float*)d_in[3];
    const float* bnw  = (const float*)d_in[4];
    const float* bnb  = (const float*)d_in[5];
    const float* fcw  = (const float*)d_in[6];
    const float* fcb  = (const float*)d_in[7];
    float* out = (float*)d_out;
    float* ws  = (float*)d_ws;

    hipLaunchKernelGGL(k_init, dim3(5), dim3(256), 0, stream, ws);
    if (ws_size >= WS_NEED_BYTES) {
        hipLaunchKernelGGL(k_pad, dim3((PW * PW + 255) / 256, 16), dim3(256), 0, stream,
                           x, ws);
        hipLaunchKernelGGL((k_convp<0>), dim3(64, 16, 2), dim3(256), 0, stream, cw, cb, ws);
        hipLaunchKernelGGL(k_stats, dim3(1), dim3(64), 0, stream, bnw, bnb, ws);
        hipLaunchKernelGGL((k_convp<1>), dim3(64, 16, 2), dim3(256), 0, stream, cw, cb, ws);
    } else {
        hipLaunchKernelGGL((k_conv<0>), dim3(64, 16), dim3(256), 0, stream, x, cw, cb, ws);
        hipLaunchKernelGGL(k_stats, dim3(1), dim3(64), 0, stream, bnw, bnb, ws);
        hipLaunchKernelGGL((k_conv<1>), dim3(64, 16), dim3(256), 0, stream, x, cw, cb, ws);
    }
    hipLaunchKernelGGL(k_volt, dim3(1), dim3(256), 0, stream, fcw, fcb, ws);
    hipLaunchKernelGGL(k_apply, dim3(4096), dim3(256), 0, stream, xhsi, ws, out);
}